// Round 11
// baseline (202.242 us; speedup 1.0000x reference)
//
#include <hip/hip_runtime.h>
#include <hip/hip_bf16.h>

#define EMB 768
#define HD 96
#define NH 8
#define SEQ 2048
#define SCALING 0.10206207261596575f   // 96^-0.5

typedef short bf16x8 __attribute__((ext_vector_type(8)));
typedef float f32x4  __attribute__((ext_vector_type(4)));
typedef unsigned short u16v8 __attribute__((ext_vector_type(8)));
typedef unsigned short u16v4 __attribute__((ext_vector_type(4)));

union F4 { float4 v; float f[4]; };

__device__ __forceinline__ unsigned short f2bf(float v) {
    __hip_bfloat16 b = __float2bfloat16(v);
    return *reinterpret_cast<unsigned short*>(&b);
}
__device__ __forceinline__ float bf2f(unsigned short u) {
    __hip_bfloat16 b = *reinterpret_cast<__hip_bfloat16*>(&u);
    return __bfloat162float(b);
}

// async global->LDS DMA, 16 B/lane. LDS dest = wave-uniform base + lane*16.
__device__ __forceinline__ void dma16(const unsigned short* g, unsigned short* l) {
    __builtin_amdgcn_global_load_lds(
        (const __attribute__((address_space(1))) unsigned int*)g,
        (__attribute__((address_space(3))) unsigned int*)l,
        16, 0, 0);
}

// ---------------------------------------------------------------------------
// convert_all: merged convert_x + convert_wT (one dispatch).
// ---------------------------------------------------------------------------
__global__ __launch_bounds__(256) void convert_all(
    const float* __restrict__ x,
    const float* __restrict__ Wq, const float* __restrict__ Wk,
    const float* __restrict__ Wv, const float* __restrict__ Wo,
    unsigned short* __restrict__ xh, unsigned short* __restrict__ xl,
    unsigned short* __restrict__ WhT, unsigned short* __restrict__ WlT)
{
    __shared__ float T[64][68];
    if (blockIdx.x < 1536) {
        const size_t i0 = ((size_t)blockIdx.x * 256 + threadIdx.x) * 8;
        F4 a, b;
        a.v = *(const float4*)&x[i0];
        b.v = *(const float4*)&x[i0 + 4];
        u16v8 h, l;
        #pragma unroll
        for (int j = 0; j < 4; j++) {
            unsigned short hu = f2bf(a.f[j]);
            h[j] = hu; l[j] = f2bf(a.f[j] - bf2f(hu));
        }
        #pragma unroll
        for (int j = 0; j < 4; j++) {
            unsigned short hu = f2bf(b.f[j]);
            h[4+j] = hu; l[4+j] = f2bf(b.f[j] - bf2f(hu));
        }
        *(u16v8*)&xh[i0] = h;
        *(u16v8*)&xl[i0] = l;
    } else {
        const int tb = blockIdx.x - 1536;      // 0..575
        const int z  = tb / 144;               // matrix 0..3
        const int r2 = tb - z*144;
        const int bx = r2 / 12, by = r2 - bx*12;
        const float* W = (z == 0) ? Wq : (z == 1) ? Wk : (z == 2) ? Wv : Wo;
        unsigned short* oh = WhT + (size_t)z * 589824;
        unsigned short* ol = WlT + (size_t)z * 589824;
        const int t = threadIdx.x;
        const int r = t >> 2, cg = (t & 3) * 16;
        const int k0 = bx * 64, n0 = by * 64;
        #pragma unroll
        for (int i = 0; i < 4; i++) {
            float4 v = *(const float4*)&W[(size_t)(k0 + r) * EMB + n0 + cg + 4*i];
            *(float4*)&T[r][cg + 4*i] = v;
        }
        __syncthreads();
        #pragma unroll
        for (int i = 0; i < 4; i++) {
            u16v4 h, l;
            #pragma unroll
            for (int j = 0; j < 4; j++) {
                float v = T[cg + 4*i + j][r];
                unsigned short hu = f2bf(v);
                h[j] = hu; l[j] = f2bf(v - bf2f(hu));
            }
            *(u16v4*)&oh[(size_t)(n0 + r) * EMB + k0 + cg + 4*i] = h;
            *(u16v4*)&ol[(size_t)(n0 + r) * EMB + k0 + cg + 4*i] = l;
        }
    }
}

// ---------------------------------------------------------------------------
// qkv_mfma v5 (unchanged from R10, ~52.4us): 128x96 head-aligned tile,
// grid 32x8x3 = 768 = exactly 3/CU, v2-safe addressing.
// ---------------------------------------------------------------------------
#define QA_H 0
#define QA_L 4096
#define QW_H 8192
#define QW_L 11264
// total 14336 shorts = 28,672 B

__global__ __launch_bounds__(256, 3) void qkv_mfma(
    const unsigned short* __restrict__ xh, const unsigned short* __restrict__ xl,
    const unsigned short* __restrict__ WhT, const unsigned short* __restrict__ WlT,
    const float* __restrict__ bq, const float* __restrict__ bk, const float* __restrict__ bv,
    unsigned short* __restrict__ Qh, unsigned short* __restrict__ Ql,
    unsigned short* __restrict__ Kb, unsigned short* __restrict__ Vt)
{
    const int which = blockIdx.z;
    const unsigned short* Wh = WhT + (size_t)which * 589824;
    const unsigned short* Wl = WlT + (size_t)which * 589824;
    const float* bias = (which == 0) ? bq : (which == 1) ? bk : bv;

    __shared__ __align__(16) unsigned short lds[14336];
    const int tid = threadIdx.x;
    const int lane = tid & 63, lo = lane & 15, h4 = lane >> 4;
    const int w = tid >> 6, wm = w & 1, wn = w >> 1;
    const int row0 = blockIdx.x * 128;
    const int head = blockIdx.y;              // col block == head
    const int col0 = head * HD;

    const unsigned short* sbase =
        (w == 0) ? xh + (size_t)row0 * EMB :
        (w == 1) ? xl + (size_t)row0 * EMB :
        (w == 2) ? Wh + (size_t)col0 * EMB :
                   Wl + (size_t)col0 * EMB;
    const int soff = (w == 0) ? QA_H : (w == 1) ? QA_L : (w == 2) ? QW_H : QW_L;
    const int jmax = (w < 2) ? 8 : 6;         // A: 128 rows, W: 96 rows

    f32x4 acc[4][3];
    #pragma unroll
    for (int i = 0; i < 4; i++)
        #pragma unroll
        for (int j = 0; j < 3; j++) acc[i][j] = (f32x4){0.f, 0.f, 0.f, 0.f};

    for (int k0 = 0; k0 < EMB; k0 += 32) {
        #pragma unroll
        for (int j = 0; j < 8; j++) {
            if (j < jmax) {                    // wave-uniform predicate
                const int u = j*64 + lane;
                const int row = u >> 2, c8 = (u & 3) * 8;
                dma16(sbase + (size_t)row * EMB + k0 + c8, &lds[soff + j*512]);
            }
        }
        __syncthreads();

        bf16x8 ah[4], al[4];
        #pragma unroll
        for (int i = 0; i < 4; i++)
            ah[i] = *(const bf16x8*)&lds[QA_H + (64*wm + 16*i + lo)*32 + 8*h4];
        if (which <= 1) {
            #pragma unroll
            for (int i = 0; i < 4; i++)
                al[i] = *(const bf16x8*)&lds[QA_L + (64*wm + 16*i + lo)*32 + 8*h4];
        }
        #pragma unroll
        for (int j = 0; j < 3; j++) {
            bf16x8 whf = *(const bf16x8*)&lds[QW_H + (48*wn + 16*j + lo)*32 + 8*h4];
            #pragma unroll
            for (int i = 0; i < 4; i++)
                acc[i][j] = __builtin_amdgcn_mfma_f32_16x16x32_bf16(ah[i], whf, acc[i][j], 0, 0, 0);
            if (which <= 1) {
                #pragma unroll
                for (int i = 0; i < 4; i++)
                    acc[i][j] = __builtin_amdgcn_mfma_f32_16x16x32_bf16(al[i], whf, acc[i][j], 0, 0, 0);
            }
            if (which != 1) {
                bf16x8 wlf = *(const bf16x8*)&lds[QW_L + (48*wn + 16*j + lo)*32 + 8*h4];
                #pragma unroll
                for (int i = 0; i < 4; i++)
                    acc[i][j] = __builtin_amdgcn_mfma_f32_16x16x32_bf16(ah[i], wlf, acc[i][j], 0, 0, 0);
            }
        }
        __syncthreads();
    }

    if (which == 0) {
        #pragma unroll
        for (int i = 0; i < 4; i++)
            #pragma unroll
            for (int r = 0; r < 4; r++) {
                const int sg = row0 + 64*wm + 16*i + 4*h4 + r;
                const int b = sg >> 11, s = sg & 2047;
                #pragma unroll
                for (int j = 0; j < 3; j++) {
                    const int d = 48*wn + 16*j + lo;
                    float v = acc[i][j][r] + bias[col0 + d];
                    unsigned short hu = f2bf(v);
                    const size_t base = ((size_t)(b*NH + head) * SEQ + s) * HD + d;
                    Qh[base] = hu;
                    Ql[base] = f2bf(v - bf2f(hu));
                }
            }
    } else if (which == 1) {
        #pragma unroll
        for (int i = 0; i < 4; i++)
            #pragma unroll
            for (int r = 0; r < 4; r++) {
                const int sg = row0 + 64*wm + 16*i + 4*h4 + r;
                const int b = sg >> 11, s = sg & 2047;
                #pragma unroll
                for (int j = 0; j < 3; j++) {
                    const int d = 48*wn + 16*j + lo;
                    float v = acc[i][j][r] + bias[col0 + d];
                    Kb[((size_t)(b*NH + head) * SEQ + s) * HD + d] = f2bf(v);
                }
            }
    } else {
        #pragma unroll
        for (int i = 0; i < 4; i++)
            #pragma unroll
            for (int r = 0; r < 4; r++) {
                const int sg = row0 + 64*wm + 16*i + 4*h4 + r;
                const int b = sg >> 11, s = sg & 2047;
                #pragma unroll
                for (int j = 0; j < 3; j++) {
                    const int d = 48*wn + 16*j + lo;
                    float v = acc[i][j][r] + bias[col0 + d];
                    Vt[((size_t)(b*NH + head) * HD + d) * SEQ + s] = f2bf(v);
                }
            }
    }
}

// ---------------------------------------------------------------------------
// proj_mfma v3 (unchanged): 64x64 tile, grid 64x12 = 768 = 3/CU balanced.
// ---------------------------------------------------------------------------
#define PA_O 0
#define PWH_O 2048
#define PWL_O 4096
// total 6144 shorts = 12,288 B

__global__ __launch_bounds__(256, 3) void proj_mfma(
    const unsigned short* __restrict__ AOh,
    const unsigned short* __restrict__ Wh, const unsigned short* __restrict__ Wl,
    const float* __restrict__ bo, float* __restrict__ out)
{
    __shared__ __align__(16) unsigned short lds[6144];
    const int tid = threadIdx.x;
    const int lane = tid & 63, lo = lane & 15, h4 = lane >> 4;
    const int w = tid >> 6, wm = w & 1, wn = w >> 1;
    const int row0 = blockIdx.x * 64, col0 = blockIdx.y * 64;
    const int r16 = lane >> 2, c8 = (lane & 3) * 8;

    f32x4 acc[2][2];
    #pragma unroll
    for (int i = 0; i < 2; i++)
        #pragma unroll
        for (int j = 0; j < 2; j++) acc[i][j] = (f32x4){0.f, 0.f, 0.f, 0.f};

    for (int k0 = 0; k0 < EMB; k0 += 32) {
        // staging: 12 units; wave w owns units 3w..3w+2.
        #pragma unroll
        for (int jj = 0; jj < 3; jj++) {
            const int u = w*3 + jj;
            const unsigned short* g; int ld;
            if (u < 4)      { g = AOh + (size_t)(row0 + u*16     + r16) * EMB + k0 + c8; ld = PA_O  + u*512; }
            else if (u < 8) { g = Wh  + (size_t)(col0 + (u-4)*16 + r16) * EMB + k0 + c8; ld = PWH_O + (u-4)*512; }
            else            { g = Wl  + (size_t)(col0 + (u-8)*16 + r16) * EMB + k0 + c8; ld = PWL_O + (u-8)*512; }
            dma16(g, &lds[ld]);
        }
        __syncthreads();

        bf16x8 af[2];
        #pragma unroll
        for (int i = 0; i < 2; i++)
            af[i] = *(const bf16x8*)&lds[PA_O + (32*wm + 16*i + lo)*32 + 8*h4];
        #pragma unroll
        for (int j = 0; j < 2; j++) {
            bf16x8 whf = *(const bf16x8*)&lds[PWH_O + (32*wn + 16*j + lo)*32 + 8*h4];
            bf16x8 wlf = *(const bf16x8*)&lds[PWL_O + (32*wn + 16*j + lo)*32 + 8*h4];
            #pragma unroll
            for (int i = 0; i < 2; i++) {
                acc[i][j] = __builtin_amdgcn_mfma_f32_16x16x32_bf16(af[i], whf, acc[i][j], 0, 0, 0);
                acc[i][j] = __builtin_amdgcn_mfma_f32_16x16x32_bf16(af[i], wlf, acc[i][j], 0, 0, 0);
            }
        }
        __syncthreads();
    }

    #pragma unroll
    for (int i = 0; i < 2; i++)
        #pragma unroll
        for (int r = 0; r < 4; r++) {
            const int sg = row0 + 32*wm + 16*i + 4*h4 + r;
            #pragma unroll
            for (int j = 0; j < 2; j++) {
                const int c = col0 + 32*wn + 16*j + lo;
                out[(size_t)sg * EMB + c] = acc[i][j][r] + bo[c];
            }
        }
}

// ---------------------------------------------------------------------------
// Flash attention v17: 2 blocks/CU via 256-thread blocks + DMA staging.
// R19 evidence: v11 (1 block/CU, 145KB LDS) phase-locks all 8 waves at each
// pair-barrier -- every drain idles the whole CU. Fix: 256-thread blocks
// (4 waves, 64 q-rows, dual-group g=w>>1 over chunk parity), grid 512 =
// 2 independent blocks/CU; while block A drains its stage, block B computes.
// Staging via global_load_lds (12 dma16/thread/iter, zero staging regs --
// avoids v15's sink-to-use collapse and removes all ds_write staging
// traffic). Single-buffered K/V pair, 2 barriers/iter:
//   compute(pair u) -> barrier -> dma(pair u+1) -> barrier (vmcnt auto).
// dma16 needs linear LDS: K [64][96] unpadded (stride 96 shorts = 48 dwords
// == 16 mod 32 -> K-reads at the 8-dword/bank minimum, conflict-free);
// V [96][64] (stride 64 == 0 mod 32 -> 2-way on reads, free per m136).
// LDS = pair 49,152 B + P 4x[32][72] 18,432 B = 67,584 B -> 2 blocks/CU.
// Tripwire: WRITE_SIZE must stay 6.1MB (spill detector).
// ---------------------------------------------------------------------------
#define ACHU 12288        // shorts per chunk (K 64x96 + V 96x64, unpadded)
#define AP_OFF 24576      // P: 4 waves x [32][72] = 9216 shorts
                          // total 33792 shorts = 67,584 B

__global__ __launch_bounds__(256, 2) void attn_mfma(
    const unsigned short* __restrict__ Qh, const unsigned short* __restrict__ Ql,
    const unsigned short* __restrict__ Kb, const unsigned short* __restrict__ Vt,
    unsigned short* __restrict__ AOh)
{
    __shared__ __align__(16) unsigned short lds[33792];
    const int id   = blockIdx.x;              // 0..511
    const int xcd  = id & 7;
    const int j    = id >> 3;                 // 0..63
    const int bh   = 2*xcd + (j & 1);         // 2 heads per XCD (L2 pinning)
    const int q0   = (j >> 1) * 64;           // 32 q-tiles of 64 rows
    const int tid  = threadIdx.x;             // 0..255
    const int w    = tid >> 6;                // wave 0..3
    const int g    = w >> 1;                  // chunk-parity group
    const int wq   = w & 1;                   // q sub-tile: rows [32wq, 32wq+32)
    const int lane = tid & 63;
    const int lo   = lane & 15;
    const int h4   = lane >> 4;

    const unsigned short* KbH = Kb + (size_t)bh * SEQ * HD;
    const unsigned short* VtH = Vt + (size_t)bh * HD * SEQ;

    // DMA staging map: vector v = tid + 256*r (r<12) covers one chunk pair
    // (3072 x 16B). LDS image is linear in v (slot = v*8 shorts):
    //   v in [0,768): K ch0 rows (kk = v/12, g8 = v%12)
    //   v in [768,1536): V ch0 (dV = uv>>3, c8 = uv&7)
    //   then ch1. All range boundaries are multiples of 64 -> wave-uniform.
    const unsigned short* sp0[12];  // per-lane global src at pair 0
    int fadv[12];                   // src advance per k-unit: HD for K, 1 for V
    #pragma unroll
    for (int r = 0; r < 12; r++) {
        const int e  = tid + 256*r;            // 0..3071
        const int ch = (e >= 1536) ? 1 : 0;
        const int e2 = e - ch*1536;
        if (e2 < 768) {
            const int kk = e2 / 12, g8 = e2 - kk*12;
            sp0[r]  = KbH + (size_t)(ch*64 + kk) * HD + 8*g8;
            fadv[r] = HD;
        } else {
            const int uv = e2 - 768, dV = uv >> 3, c8 = uv & 7;
            sp0[r]  = VtH + (size_t)dV*SEQ + ch*64 + 8*c8;
            fadv[r] = 1;
        }
    }

    // Q fragments register-resident for this wave's 32 rows
    bf16x8 qhf[2][3], qlf[2][3];
    #pragma unroll
    for (int mi = 0; mi < 2; mi++) {
        const size_t qoff = ((size_t)bh*SEQ + q0 + 32*wq + 16*mi + lo) * HD + 8*h4;
        #pragma unroll
        for (int ks = 0; ks < 3; ks++) {
            qhf[mi][ks] = *(const bf16x8*)&Qh[qoff + 32*ks];
            qlf[mi][ks] = *(const bf16x8*)&Ql[qoff + 32*ks];
        }
    }

    f32x4 O[2][6];
    #pragma unroll
    for (int mi = 0; mi < 2; mi++)
        #pragma unroll
        for (int i = 0; i < 6; i++) O[mi][i] = (f32x4){0.f, 0.f, 0.f, 0.f};
    float lsum[2][4] = {};

    unsigned short* Pw = lds + AP_OFF + w * 2304;     // wave-private [32][72]

    // ---- prologue: DMA pair 0 ----
    #pragma unroll
    for (int r = 0; r < 12; r++)
        dma16(sp0[r], &lds[(tid >> 6)*512 + r*2048]);
    __syncthreads();

    #pragma unroll 1
    for (int u = 0; u < 16; u++) {
        // my chunk = 2u + g, resident in single pair buffer
        const unsigned short* myK = lds + g*ACHU;
        const unsigned short* myV = myK + 6144;

        // ---- S = Q K^T (2-term split), K from LDS [64][96] ----
        f32x4 S[2][4];
        #pragma unroll
        for (int mi = 0; mi < 2; mi++)
            #pragma unroll
            for (int nb = 0; nb < 4; nb++) S[mi][nb] = (f32x4){0.f, 0.f, 0.f, 0.f};
        __builtin_amdgcn_s_setprio(1);
        #pragma unroll
        for (int ks = 0; ks < 3; ks++) {
            bf16x8 kf[4];
            #pragma unroll
            for (int nb = 0; nb < 4; nb++)
                kf[nb] = *(const bf16x8*)&myK[(16*nb + lo)*96 + 32*ks + 8*h4];
            #pragma unroll
            for (int nb = 0; nb < 4; nb++)
                #pragma unroll
                for (int mi = 0; mi < 2; mi++) {
                    S[mi][nb] = __builtin_amdgcn_mfma_f32_16x16x32_bf16(qhf[mi][ks], kf[nb], S[mi][nb], 0, 0, 0);
                    S[mi][nb] = __builtin_amdgcn_mfma_f32_16x16x32_bf16(qlf[mi][ks], kf[nb], S[mi][nb], 0, 0, 0);
                }
        }
        __builtin_amdgcn_s_setprio(0);

        // ---- P = exp(S), partial row-sums, P -> wave-private LDS ----
        #pragma unroll
        for (int mi = 0; mi < 2; mi++)
            #pragma unroll
            for (int nb = 0; nb < 4; nb++)
                #pragma unroll
                for (int r = 0; r < 4; r++) {
                    float p = __expf(S[mi][nb][r]);
                    lsum[mi][r] += p;
                    Pw[(16*mi + 4*h4 + r)*72 + 16*nb + lo] = f2bf(p);
                }

        // ---- O += P V, V from LDS [96][64] ----
        __builtin_amdgcn_s_setprio(1);
        #pragma unroll
        for (int ks2 = 0; ks2 < 2; ks2++) {
            bf16x8 pf0 = *(const bf16x8*)&Pw[(lo)*72      + 32*ks2 + 8*h4];
            bf16x8 pf1 = *(const bf16x8*)&Pw[(16 + lo)*72 + 32*ks2 + 8*h4];
            #pragma unroll
            for (int nb2 = 0; nb2 < 6; nb2++) {
                bf16x8 vfv = *(const bf16x8*)&myV[(16*nb2 + lo)*64 + 32*ks2 + 8*h4];
                O[0][nb2] = __builtin_amdgcn_mfma_f32_16x16x32_bf16(pf0, vfv, O[0][nb2], 0, 0, 0);
                O[1][nb2] = __builtin_amdgcn_mfma_f32_16x16x32_bf16(pf1, vfv, O[1][nb2], 0, 0, 0);
            }
        }
        __builtin_amdgcn_s_setprio(0);

        __syncthreads();                       // all reads of pair u done

        if (u < 15) {                          // DMA pair u+1 over same buffer
            const size_t adv = (size_t)(u + 1) * 128;
            #pragma unroll
            for (int r = 0; r < 12; r++)
                dma16(sp0[r] + adv * fadv[r], &lds[(tid >> 6)*512 + r*2048]);
        }
        __syncthreads();                       // dma drained (vmcnt) + visible
    }

    // ---- combine epilogue: group 1 dumps partials, group 0 adds & stores ----
    // Fo [64 q][96 d] f32 (24,576 B) + Ls [64 q][16] f32 (4,096 B) alias the
    // chunk region (49,152 B); last loop barrier precedes this reuse.
    float* Fo = (float*)lds;
    float* Ls = (float*)lds + 6144;
    if (g == 1) {
        #pragma unroll
        for (int mi = 0; mi < 2; mi++)
            #pragma unroll
            for (int r = 0; r < 4; r++) {
                const int ql = 32*wq + 16*mi + 4*h4 + r;
                Ls[ql*16 + lo] = lsum[mi][r];
                #pragma unroll
                for (int nb2 = 0; nb2 < 6; nb2++)
                    Fo[ql*96 + 16*nb2 + lo] = O[mi][nb2][r];
            }
    }
    __syncthreads();
    if (g == 0) {
        const int b = bh >> 3, hh = bh & 7;
        #pragma unroll
        for (int mi = 0; mi < 2; mi++)
            #pragma unroll
            for (int r = 0; r < 4; r++) {
                const int ql = 32*wq + 16*mi + 4*h4 + r;
                float l = lsum[mi][r] + Ls[ql*16 + lo];
                l += __shfl_xor(l, 1);
                l += __shfl_xor(l, 2);
                l += __shfl_xor(l, 4);
                l += __shfl_xor(l, 8);
                const float sc = SCALING / l;
                const int q = q0 + ql;
                const size_t base = ((size_t)b*SEQ + q)*EMB + hh*HD + lo;
                #pragma unroll
                for (int nb2 = 0; nb2 < 6; nb2++)
                    AOh[base + 16*nb2] = f2bf((O[mi][nb2][r] + Fo[ql*96 + 16*nb2 + lo]) * sc);
            }
    }
}

// ---------------------------------------------------------------------------
extern "C" void kernel_launch(void* const* d_in, const int* in_sizes, int n_in,
                              void* d_out, int out_size, void* d_ws, size_t ws_size,
                              hipStream_t stream)
{
    const float* x  = (const float*)d_in[0];
    const float* Wq = (const float*)d_in[1];
    const float* bq = (const float*)d_in[2];
    const float* Wk = (const float*)d_in[3];
    const float* bk = (const float*)d_in[4];
    const float* Wv = (const float*)d_in[5];
    const float* bv = (const float*)d_in[6];
    const float* Wo = (const float*)d_in[7];
    const float* bo = (const float*)d_in[8];
    float* out = (float*)d_out;

    unsigned short* ws = (unsigned short*)d_ws;
    const size_t HS = (size_t)16 * SEQ * HD;       // 3,145,728 shorts
    const size_t WS1 = (size_t)EMB * EMB;          // 589,824
    unsigned short* Qh  = ws;
    unsigned short* Ql  = ws + HS;
    unsigned short* Kb  = ws + 2*HS;
    unsigned short* Vt  = ws + 3*HS;
    unsigned short* xh  = ws + 4*HS;               // dead after qkv -> AOh
    unsigned short* xl  = ws + 5*HS;
    unsigned short* WhT = ws + 6*HS;
    unsigned short* WlT = ws + 6*HS + 4*WS1;
    unsigned short* AOh = xh;

    convert_all<<<2112, 256, 0, stream>>>(x, Wq, Wk, Wv, Wo, xh, xl, WhT, WlT);
    qkv_mfma<<<dim3(32, 8, 3), 256, 0, stream>>>(xh, xl, WhT, WlT, bq, bk, bv,
                                                 Qh, Ql, Kb, Vt);
    attn_mfma<<<512, 256, 0, stream>>>(Qh, Ql, Kb, Vt, AOh);
    proj_mfma<<<dim3(64, 12), 256, 0, stream>>>(AOh, WhT + 3*WS1, WlT + 3*WS1, bo, out);
}

// Round 12
// 198.231 us; speedup vs baseline: 1.0202x; 1.0202x over previous
//
#include <hip/hip_runtime.h>
#include <hip/hip_bf16.h>

#define EMB 768
#define HD 96
#define NH 8
#define SEQ 2048
#define SCALING 0.10206207261596575f   // 96^-0.5

typedef short bf16x8 __attribute__((ext_vector_type(8)));
typedef float f32x4  __attribute__((ext_vector_type(4)));
typedef unsigned short u16v8 __attribute__((ext_vector_type(8)));
typedef unsigned short u16v4 __attribute__((ext_vector_type(4)));

union F4 { float4 v; float f[4]; };

__device__ __forceinline__ unsigned short f2bf(float v) {
    __hip_bfloat16 b = __float2bfloat16(v);
    return *reinterpret_cast<unsigned short*>(&b);
}
__device__ __forceinline__ float bf2f(unsigned short u) {
    __hip_bfloat16 b = *reinterpret_cast<__hip_bfloat16*>(&u);
    return __bfloat162float(b);
}

// async global->LDS DMA, 16 B/lane. LDS dest = wave-uniform base + lane*16.
__device__ __forceinline__ void dma16(const unsigned short* g, unsigned short* l) {
    __builtin_amdgcn_global_load_lds(
        (const __attribute__((address_space(1))) unsigned int*)g,
        (__attribute__((address_space(3))) unsigned int*)l,
        16, 0, 0);
}

// ---------------------------------------------------------------------------
// convert_all: merged convert_x + convert_wT (one dispatch).
// ---------------------------------------------------------------------------
__global__ __launch_bounds__(256) void convert_all(
    const float* __restrict__ x,
    const float* __restrict__ Wq, const float* __restrict__ Wk,
    const float* __restrict__ Wv, const float* __restrict__ Wo,
    unsigned short* __restrict__ xh, unsigned short* __restrict__ xl,
    unsigned short* __restrict__ WhT, unsigned short* __restrict__ WlT)
{
    __shared__ float T[64][68];
    if (blockIdx.x < 1536) {
        const size_t i0 = ((size_t)blockIdx.x * 256 + threadIdx.x) * 8;
        F4 a, b;
        a.v = *(const float4*)&x[i0];
        b.v = *(const float4*)&x[i0 + 4];
        u16v8 h, l;
        #pragma unroll
        for (int j = 0; j < 4; j++) {
            unsigned short hu = f2bf(a.f[j]);
            h[j] = hu; l[j] = f2bf(a.f[j] - bf2f(hu));
        }
        #pragma unroll
        for (int j = 0; j < 4; j++) {
            unsigned short hu = f2bf(b.f[j]);
            h[4+j] = hu; l[4+j] = f2bf(b.f[j] - bf2f(hu));
        }
        *(u16v8*)&xh[i0] = h;
        *(u16v8*)&xl[i0] = l;
    } else {
        const int tb = blockIdx.x - 1536;      // 0..575
        const int z  = tb / 144;               // matrix 0..3
        const int r2 = tb - z*144;
        const int bx = r2 / 12, by = r2 - bx*12;
        const float* W = (z == 0) ? Wq : (z == 1) ? Wk : (z == 2) ? Wv : Wo;
        unsigned short* oh = WhT + (size_t)z * 589824;
        unsigned short* ol = WlT + (size_t)z * 589824;
        const int t = threadIdx.x;
        const int r = t >> 2, cg = (t & 3) * 16;
        const int k0 = bx * 64, n0 = by * 64;
        #pragma unroll
        for (int i = 0; i < 4; i++) {
            float4 v = *(const float4*)&W[(size_t)(k0 + r) * EMB + n0 + cg + 4*i];
            *(float4*)&T[r][cg + 4*i] = v;
        }
        __syncthreads();
        #pragma unroll
        for (int i = 0; i < 4; i++) {
            u16v4 h, l;
            #pragma unroll
            for (int j = 0; j < 4; j++) {
                float v = T[cg + 4*i + j][r];
                unsigned short hu = f2bf(v);
                h[j] = hu; l[j] = f2bf(v - bf2f(hu));
            }
            *(u16v4*)&oh[(size_t)(n0 + r) * EMB + k0 + cg + 4*i] = h;
            *(u16v4*)&ol[(size_t)(n0 + r) * EMB + k0 + cg + 4*i] = l;
        }
    }
}

// ---------------------------------------------------------------------------
// qkv_mfma v5 (~52.4us): 128x96 head-aligned tile, grid 32x8x3 = 768 =
// exactly 3/CU, v2-safe addressing (one sbase/wave, offsets recomputed).
// ---------------------------------------------------------------------------
#define QA_H 0
#define QA_L 4096
#define QW_H 8192
#define QW_L 11264
// total 14336 shorts = 28,672 B

__global__ __launch_bounds__(256, 3) void qkv_mfma(
    const unsigned short* __restrict__ xh, const unsigned short* __restrict__ xl,
    const unsigned short* __restrict__ WhT, const unsigned short* __restrict__ WlT,
    const float* __restrict__ bq, const float* __restrict__ bk, const float* __restrict__ bv,
    unsigned short* __restrict__ Qh, unsigned short* __restrict__ Ql,
    unsigned short* __restrict__ Kb, unsigned short* __restrict__ Vt)
{
    const int which = blockIdx.z;
    const unsigned short* Wh = WhT + (size_t)which * 589824;
    const unsigned short* Wl = WlT + (size_t)which * 589824;
    const float* bias = (which == 0) ? bq : (which == 1) ? bk : bv;

    __shared__ __align__(16) unsigned short lds[14336];
    const int tid = threadIdx.x;
    const int lane = tid & 63, lo = lane & 15, h4 = lane >> 4;
    const int w = tid >> 6, wm = w & 1, wn = w >> 1;
    const int row0 = blockIdx.x * 128;
    const int head = blockIdx.y;              // col block == head
    const int col0 = head * HD;

    const unsigned short* sbase =
        (w == 0) ? xh + (size_t)row0 * EMB :
        (w == 1) ? xl + (size_t)row0 * EMB :
        (w == 2) ? Wh + (size_t)col0 * EMB :
                   Wl + (size_t)col0 * EMB;
    const int soff = (w == 0) ? QA_H : (w == 1) ? QA_L : (w == 2) ? QW_H : QW_L;
    const int jmax = (w < 2) ? 8 : 6;         // A: 128 rows, W: 96 rows

    f32x4 acc[4][3];
    #pragma unroll
    for (int i = 0; i < 4; i++)
        #pragma unroll
        for (int j = 0; j < 3; j++) acc[i][j] = (f32x4){0.f, 0.f, 0.f, 0.f};

    for (int k0 = 0; k0 < EMB; k0 += 32) {
        #pragma unroll
        for (int j = 0; j < 8; j++) {
            if (j < jmax) {                    // wave-uniform predicate
                const int u = j*64 + lane;
                const int row = u >> 2, c8 = (u & 3) * 8;
                dma16(sbase + (size_t)row * EMB + k0 + c8, &lds[soff + j*512]);
            }
        }
        __syncthreads();

        bf16x8 ah[4], al[4];
        #pragma unroll
        for (int i = 0; i < 4; i++)
            ah[i] = *(const bf16x8*)&lds[QA_H + (64*wm + 16*i + lo)*32 + 8*h4];
        if (which <= 1) {
            #pragma unroll
            for (int i = 0; i < 4; i++)
                al[i] = *(const bf16x8*)&lds[QA_L + (64*wm + 16*i + lo)*32 + 8*h4];
        }
        #pragma unroll
        for (int j = 0; j < 3; j++) {
            bf16x8 whf = *(const bf16x8*)&lds[QW_H + (48*wn + 16*j + lo)*32 + 8*h4];
            #pragma unroll
            for (int i = 0; i < 4; i++)
                acc[i][j] = __builtin_amdgcn_mfma_f32_16x16x32_bf16(ah[i], whf, acc[i][j], 0, 0, 0);
            if (which <= 1) {
                #pragma unroll
                for (int i = 0; i < 4; i++)
                    acc[i][j] = __builtin_amdgcn_mfma_f32_16x16x32_bf16(al[i], whf, acc[i][j], 0, 0, 0);
            }
            if (which != 1) {
                bf16x8 wlf = *(const bf16x8*)&lds[QW_L + (48*wn + 16*j + lo)*32 + 8*h4];
                #pragma unroll
                for (int i = 0; i < 4; i++)
                    acc[i][j] = __builtin_amdgcn_mfma_f32_16x16x32_bf16(ah[i], wlf, acc[i][j], 0, 0, 0);
            }
        }
        __syncthreads();
    }

    if (which == 0) {
        #pragma unroll
        for (int i = 0; i < 4; i++)
            #pragma unroll
            for (int r = 0; r < 4; r++) {
                const int sg = row0 + 64*wm + 16*i + 4*h4 + r;
                const int b = sg >> 11, s = sg & 2047;
                #pragma unroll
                for (int j = 0; j < 3; j++) {
                    const int d = 48*wn + 16*j + lo;
                    float v = acc[i][j][r] + bias[col0 + d];
                    unsigned short hu = f2bf(v);
                    const size_t base = ((size_t)(b*NH + head) * SEQ + s) * HD + d;
                    Qh[base] = hu;
                    Ql[base] = f2bf(v - bf2f(hu));
                }
            }
    } else if (which == 1) {
        #pragma unroll
        for (int i = 0; i < 4; i++)
            #pragma unroll
            for (int r = 0; r < 4; r++) {
                const int sg = row0 + 64*wm + 16*i + 4*h4 + r;
                const int b = sg >> 11, s = sg & 2047;
                #pragma unroll
                for (int j = 0; j < 3; j++) {
                    const int d = 48*wn + 16*j + lo;
                    float v = acc[i][j][r] + bias[col0 + d];
                    Kb[((size_t)(b*NH + head) * SEQ + s) * HD + d] = f2bf(v);
                }
            }
    } else {
        #pragma unroll
        for (int i = 0; i < 4; i++)
            #pragma unroll
            for (int r = 0; r < 4; r++) {
                const int sg = row0 + 64*wm + 16*i + 4*h4 + r;
                const int b = sg >> 11, s = sg & 2047;
                #pragma unroll
                for (int j = 0; j < 3; j++) {
                    const int d = 48*wn + 16*j + lo;
                    float v = acc[i][j][r] + bias[col0 + d];
                    Vt[((size_t)(b*NH + head) * HD + d) * SEQ + s] = f2bf(v);
                }
            }
    }
}

// ---------------------------------------------------------------------------
// proj_mfma v3 (unchanged): 64x64 tile, grid 64x12 = 768 = 3/CU balanced.
// ---------------------------------------------------------------------------
#define PA_O 0
#define PWH_O 2048
#define PWL_O 4096
// total 6144 shorts = 12,288 B

__global__ __launch_bounds__(256, 3) void proj_mfma(
    const unsigned short* __restrict__ AOh,
    const unsigned short* __restrict__ Wh, const unsigned short* __restrict__ Wl,
    const float* __restrict__ bo, float* __restrict__ out)
{
    __shared__ __align__(16) unsigned short lds[6144];
    const int tid = threadIdx.x;
    const int lane = tid & 63, lo = lane & 15, h4 = lane >> 4;
    const int w = tid >> 6, wm = w & 1, wn = w >> 1;
    const int row0 = blockIdx.x * 64, col0 = blockIdx.y * 64;
    const int r16 = lane >> 2, c8 = (lane & 3) * 8;

    f32x4 acc[2][2];
    #pragma unroll
    for (int i = 0; i < 2; i++)
        #pragma unroll
        for (int j = 0; j < 2; j++) acc[i][j] = (f32x4){0.f, 0.f, 0.f, 0.f};

    for (int k0 = 0; k0 < EMB; k0 += 32) {
        // staging: 12 units; wave w owns units 3w..3w+2.
        #pragma unroll
        for (int jj = 0; jj < 3; jj++) {
            const int u = w*3 + jj;
            const unsigned short* g; int ld;
            if (u < 4)      { g = AOh + (size_t)(row0 + u*16     + r16) * EMB + k0 + c8; ld = PA_O  + u*512; }
            else if (u < 8) { g = Wh  + (size_t)(col0 + (u-4)*16 + r16) * EMB + k0 + c8; ld = PWH_O + (u-4)*512; }
            else            { g = Wl  + (size_t)(col0 + (u-8)*16 + r16) * EMB + k0 + c8; ld = PWL_O + (u-8)*512; }
            dma16(g, &lds[ld]);
        }
        __syncthreads();

        bf16x8 af[2];
        #pragma unroll
        for (int i = 0; i < 2; i++)
            af[i] = *(const bf16x8*)&lds[PA_O + (32*wm + 16*i + lo)*32 + 8*h4];
        #pragma unroll
        for (int j = 0; j < 2; j++) {
            bf16x8 whf = *(const bf16x8*)&lds[PWH_O + (32*wn + 16*j + lo)*32 + 8*h4];
            bf16x8 wlf = *(const bf16x8*)&lds[PWL_O + (32*wn + 16*j + lo)*32 + 8*h4];
            #pragma unroll
            for (int i = 0; i < 2; i++) {
                acc[i][j] = __builtin_amdgcn_mfma_f32_16x16x32_bf16(af[i], whf, acc[i][j], 0, 0, 0);
                acc[i][j] = __builtin_amdgcn_mfma_f32_16x16x32_bf16(af[i], wlf, acc[i][j], 0, 0, 0);
            }
        }
        __syncthreads();
    }

    #pragma unroll
    for (int i = 0; i < 2; i++)
        #pragma unroll
        for (int r = 0; r < 4; r++) {
            const int sg = row0 + 32*wm + 16*i + 4*h4 + r;
            #pragma unroll
            for (int j = 0; j < 2; j++) {
                const int c = col0 + 32*wn + 16*j + lo;
                out[(size_t)sg * EMB + c] = acc[i][j][r] + bo[c];
            }
        }
}

// ---------------------------------------------------------------------------
// Flash attention v11 (proven best, ~53.8us): pairwise split-K dual-group,
// all-LDS padded K/V, setprio. Design space mapped across v9-v17: this
// structure beats pair-split-16row (58.5), L2-direct (102.8), V-early
// (64.7), reg-prefetch (142.1), 2-block single-buffer DMA (57.1).
// Residual conflicts (4.18M) are mostly 2-way (free, m136); the plateau is
// the phase-locked 2-phase structure, only passable via a full 8-phase
// T-stack port.
// ---------------------------------------------------------------------------
#define ACH 13568         // shorts per chunk (K 64x104=6656 + V 96x72=6912)
#define APAIR 27136       // shorts per chunk pair
#define AP_OFF 54272      // P: 8 waves x [32][72] = 18432 shorts
                          // total 72704 shorts = 145,408 B

__global__ __launch_bounds__(512, 2) void attn_mfma(
    const unsigned short* __restrict__ Qh, const unsigned short* __restrict__ Ql,
    const unsigned short* __restrict__ Kb, const unsigned short* __restrict__ Vt,
    unsigned short* __restrict__ AOh)
{
    __shared__ __align__(16) unsigned short lds[72704];
    const int id   = blockIdx.x;
    const int xcd  = id & 7;
    const int j    = id >> 3;                 // 0..31
    const int bh   = 2*xcd + (j & 1);         // 2 heads per XCD
    const int q0   = (j >> 1) * 128;          // 16 q-tiles of 128 rows
    const int tid  = threadIdx.x;             // 0..511
    const int w    = tid >> 6;                // wave 0..7
    const int g    = w >> 2;                  // chunk-parity group
    const int wq   = w & 3;                   // q sub-tile: rows [32wq, 32wq+32)
    const int lane = tid & 63;
    const int lo   = lane & 15;
    const int h4   = lane >> 4;

    const unsigned short* KbH = Kb + (size_t)bh * SEQ * HD;
    const unsigned short* VtH = Vt + (size_t)bh * HD * SEQ;

    // staging map: 6 b128 elements/thread cover one chunk pair (3072 vectors).
    const unsigned short* sp0[6];   // src ptr at pair-base k-row 0
    int fK[6];                      // src advance per k-row: HD for K, 1 for V
    int doff[6];                    // dst offset within pair buffer (shorts)
    #pragma unroll
    for (int r = 0; r < 6; r++) {
        const int e  = tid + 512*r;
        const int ch = (e >= 1536) ? 1 : 0;
        const int e2 = e - ch*1536;
        if (e2 < 768) {
            const int kk = e2 / 12, g8 = e2 - kk*12;
            sp0[r]  = KbH + (size_t)(ch*64 + kk) * HD + 8*g8;
            fK[r]   = HD;
            doff[r] = ch*ACH + kk*104 + 8*g8;
        } else {
            const int uv = e2 - 768, dV = uv >> 3, c8 = uv & 7;
            sp0[r]  = VtH + (size_t)dV*SEQ + ch*64 + 8*c8;
            fK[r]   = 1;
            doff[r] = ch*ACH + 6656 + dV*72 + 8*c8;
        }
    }

    // Q fragments register-resident for this wave's 32 rows
    bf16x8 qhf[2][3], qlf[2][3];
    #pragma unroll
    for (int mi = 0; mi < 2; mi++) {
        const size_t qoff = ((size_t)bh*SEQ + q0 + 32*wq + 16*mi + lo) * HD + 8*h4;
        #pragma unroll
        for (int ks = 0; ks < 3; ks++) {
            qhf[mi][ks] = *(const bf16x8*)&Qh[qoff + 32*ks];
            qlf[mi][ks] = *(const bf16x8*)&Ql[qoff + 32*ks];
        }
    }

    f32x4 O[2][6];
    #pragma unroll
    for (int mi = 0; mi < 2; mi++)
        #pragma unroll
        for (int i = 0; i < 6; i++) O[mi][i] = (f32x4){0.f, 0.f, 0.f, 0.f};
    float lsum[2][4] = {};

    unsigned short* Pw = lds + AP_OFF + w * 2304;     // wave-private [32][72]

    // ---- stage pair 0 (chunks 0,1) into pair-buffer 0 ----
    #pragma unroll
    for (int r = 0; r < 6; r++)
        *(u16v8*)&lds[doff[r]] = *(const u16v8*)sp0[r];
    __syncthreads();

    #pragma unroll 1
    for (int u = 0; u < 16; u++) {
        // ---- prefetch pair u+1 into regs (tail: re-read pair 0, write is dead)
        const int kn0 = (u < 15) ? 128*(u + 1) : 0;
        u16v8 st[6];
        #pragma unroll
        for (int r = 0; r < 6; r++)
            st[r] = *(const u16v8*)(sp0[r] + (size_t)kn0 * fK[r]);

        // my chunk = 2u + g, resident in pair-buffer (u&1)
        const unsigned short* myK = lds + (u & 1)*APAIR + g*ACH;
        const unsigned short* myV = myK + 6656;

        // ---- S = Q K^T (2-term split) ----
        f32x4 S[2][4];
        #pragma unroll
        for (int mi = 0; mi < 2; mi++)
            #pragma unroll
            for (int nb = 0; nb < 4; nb++) S[mi][nb] = (f32x4){0.f, 0.f, 0.f, 0.f};
        __builtin_amdgcn_s_setprio(1);
        #pragma unroll
        for (int ks = 0; ks < 3; ks++) {
            bf16x8 kf[4];
            #pragma unroll
            for (int nb = 0; nb < 4; nb++)
                kf[nb] = *(const bf16x8*)&myK[(16*nb + lo)*104 + 32*ks + 8*h4];
            #pragma unroll
            for (int nb = 0; nb < 4; nb++)
                #pragma unroll
                for (int mi = 0; mi < 2; mi++) {
                    S[mi][nb] = __builtin_amdgcn_mfma_f32_16x16x32_bf16(qhf[mi][ks], kf[nb], S[mi][nb], 0, 0, 0);
                    S[mi][nb] = __builtin_amdgcn_mfma_f32_16x16x32_bf16(qlf[mi][ks], kf[nb], S[mi][nb], 0, 0, 0);
                }
        }
        __builtin_amdgcn_s_setprio(0);

        // ---- P = exp(S), partial row-sums, P -> wave-private LDS ----
        #pragma unroll
        for (int mi = 0; mi < 2; mi++)
            #pragma unroll
            for (int nb = 0; nb < 4; nb++)
                #pragma unroll
                for (int r = 0; r < 4; r++) {
                    float p = __expf(S[mi][nb][r]);
                    lsum[mi][r] += p;
                    Pw[(16*mi + 4*h4 + r)*72 + 16*nb + lo] = f2bf(p);
                }

        // ---- O += P V ----
        __builtin_amdgcn_s_setprio(1);
        #pragma unroll
        for (int ks2 = 0; ks2 < 2; ks2++) {
            bf16x8 pf0 = *(const bf16x8*)&Pw[(lo)*72      + 32*ks2 + 8*h4];
            bf16x8 pf1 = *(const bf16x8*)&Pw[(16 + lo)*72 + 32*ks2 + 8*h4];
            #pragma unroll
            for (int nb2 = 0; nb2 < 6; nb2++) {
                bf16x8 vfv = *(const bf16x8*)&myV[(16*nb2 + lo)*72 + 32*ks2 + 8*h4];
                O[0][nb2] = __builtin_amdgcn_mfma_f32_16x16x32_bf16(pf0, vfv, O[0][nb2], 0, 0, 0);
                O[1][nb2] = __builtin_amdgcn_mfma_f32_16x16x32_bf16(pf1, vfv, O[1][nb2], 0, 0, 0);
            }
        }
        __builtin_amdgcn_s_setprio(0);

        // ---- write prefetched regs to the other pair buffer ----
        unsigned short* dstp = lds + ((u + 1) & 1)*APAIR;
        #pragma unroll
        for (int r = 0; r < 6; r++)
            *(u16v8*)&dstp[doff[r]] = st[r];
        __syncthreads();
    }

    // ---- combine epilogue: group 1 dumps partials, group 0 adds & stores ----
    float* Fo = (float*)lds;                 // [128 q][96 d]   = 49,152 B
    float* Ls = (float*)lds + 12288;         // [128 q][16 lo]  =  8,192 B
    if (g == 1) {
        #pragma unroll
        for (int mi = 0; mi < 2; mi++)
            #pragma unroll
            for (int r = 0; r < 4; r++) {
                const int ql = 32*wq + 16*mi + 4*h4 + r;
                Ls[ql*16 + lo] = lsum[mi][r];
                #pragma unroll
                for (int nb2 = 0; nb2 < 6; nb2++)
                    Fo[ql*96 + 16*nb2 + lo] = O[mi][nb2][r];
            }
    }
    __syncthreads();
    if (g == 0) {
        const int b = bh >> 3, hh = bh & 7;
        #pragma unroll
        for (int mi = 0; mi < 2; mi++)
            #pragma unroll
            for (int r = 0; r < 4; r++) {
                const int ql = 32*wq + 16*mi + 4*h4 + r;
                float l = lsum[mi][r] + Ls[ql*16 + lo];
                l += __shfl_xor(l, 1);
                l += __shfl_xor(l, 2);
                l += __shfl_xor(l, 4);
                l += __shfl_xor(l, 8);
                const float sc = SCALING / l;
                const int q = q0 + ql;
                const size_t base = ((size_t)b*SEQ + q)*EMB + hh*HD + lo;
                #pragma unroll
                for (int nb2 = 0; nb2 < 6; nb2++)
                    AOh[base + 16*nb2] = f2bf((O[mi][nb2][r] + Fo[ql*96 + 16*nb2 + lo]) * sc);
            }
    }
}

// ---------------------------------------------------------------------------
extern "C" void kernel_launch(void* const* d_in, const int* in_sizes, int n_in,
                              void* d_out, int out_size, void* d_ws, size_t ws_size,
                              hipStream_t stream)
{
    const float* x  = (const float*)d_in[0];
    const float* Wq = (const float*)d_in[1];
    const float* bq = (const float*)d_in[2];
    const float* Wk = (const float*)d_in[3];
    const float* bk = (const float*)d_in[4];
    const float* Wv = (const float*)d_in[5];
    const float* bv = (const float*)d_in[6];
    const float* Wo = (const float*)d_in[7];
    const float* bo = (const float*)d_in[8];
    float* out = (float*)d_out;

    unsigned short* ws = (unsigned short*)d_ws;
    const size_t HS = (size_t)16 * SEQ * HD;       // 3,145,728 shorts
    const size_t WS1 = (size_t)EMB * EMB;          // 589,824
    unsigned short* Qh  = ws;
    unsigned short* Ql  = ws + HS;
    unsigned short* Kb  = ws + 2*HS;
    unsigned short* Vt  = ws + 3*HS;
    unsigned short* xh  = ws + 4*HS;               // dead after qkv -> AOh
    unsigned short* xl  = ws + 5*HS;
    unsigned short* WhT = ws + 6*HS;
    unsigned short* WlT = ws + 6*HS + 4*WS1;
    unsigned short* AOh = xh;

    convert_all<<<2112, 256, 0, stream>>>(x, Wq, Wk, Wv, Wo, xh, xl, WhT, WlT);
    qkv_mfma<<<dim3(32, 8, 3), 256, 0, stream>>>(xh, xl, WhT, WlT, bq, bk, bv,
                                                 Qh, Ql, Kb, Vt);
    attn_mfma<<<256, 512, 0, stream>>>(Qh, Ql, Kb, Vt, AOh);
    proj_mfma<<<dim3(64, 12), 256, 0, stream>>>(AOh, WhT + 3*WS1, WlT + 3*WS1, bo, out);
}